// Round 7
// baseline (252.480 us; speedup 1.0000x reference)
//
#include <hip/hip_runtime.h>
#include <stdint.h>
#include <stddef.h>

#define DIM 768

typedef short short8 __attribute__((ext_vector_type(8)));
typedef float f32x4 __attribute__((ext_vector_type(4)));

__device__ inline unsigned short f2bf_rne(float f) {
    union { float f; unsigned u; } x; x.f = f;
    unsigned r = x.u + 0x7fffu + ((x.u >> 16) & 1u);
    return (unsigned short)(r >> 16);
}

__device__ inline void gload_lds16(const void* g, void* l) {
    __builtin_amdgcn_global_load_lds((const __attribute__((address_space(1))) void*)g,
                                     (__attribute__((address_space(3))) void*)l, 16, 0, 0);
}

// Kernel 1: W [K][N] fp32 -> Bt [N][K] bf16 via LDS transpose (coalesced read AND write).
__global__ __launch_bounds__(256) void convw_kernel(
    const float* __restrict__ w, unsigned short* __restrict__ Bt)
{
    __shared__ unsigned short t[64][65];
    const int k0 = blockIdx.x * 64, n0 = blockIdx.y * 64;
    const int tid = threadIdx.x;
#pragma unroll
    for (int p = 0; p < 16; ++p) {
        int e = p * 256 + tid;
        int r = e >> 6, c = e & 63;
        t[c][r] = f2bf_rne(w[(size_t)(k0 + r) * DIM + n0 + c]);
    }
    __syncthreads();
#pragma unroll
    for (int p = 0; p < 16; ++p) {
        int e = p * 256 + tid;
        int r = e >> 6, c = e & 63;
        Bt[(size_t)(n0 + r) * DIM + k0 + c] = t[r][c];
    }
}

// Kernel 2: fused gather + GEMM + conditional select.
// Latency-bound (r3: MfmaUtil 7.5%, Occ 16%, FETCH=ideal). Fixes in this version:
//  1. 64x128 tile -> 1536 blocks = 5-6 blocks/CU (vs grid-limited 3): double the
//     desynced wave groups covering exposed gather latency.
//  2. A staged as BF16 via reg-staging (global->reg, convert once, swizzled
//     ds_write), 2-deep register pipeline: A(t+2) issued while computing t.
//     Pack VALU leaves the MFMA loop; LDS 24.5 KB. B stays gload_lds with
//     pre-swizzled SOURCE address (rule #21: gload_lds dest must be linear).
//  3. Both A and B LDS reads chunk-XOR-swizzled (s ^ ((r>>1)&3), verified
//     r2/r3): 2-way bank alias = free, vs 8-way linear.
// Sync: ONE barrier/K-step; counted vmcnt(2) before it (drains B gload_lds +
// consumed A regs, leaves A(t+2) in flight); sched_barrier pinning (rule #18).
// 4 waves, wave = 32m x 64n = 2x4 16x16x32 bf16 MFMA.
__global__ __launch_bounds__(256, 4) void fused_gemm_kernel(
    const int* __restrict__ token,
    const int* __restrict__ need_mapper,
    const float* __restrict__ emb,
    const unsigned short* __restrict__ Bt,   // [768][768] bf16, n-major
    const float* __restrict__ bias,
    float* __restrict__ out)                 // [M][768] fp32
{
    __shared__ unsigned short As[2][64 * 32];    // 2 x 4 KB bf16
    __shared__ unsigned short Bs[2][128 * 32];   // 2 x 8 KB bf16
    __shared__ int tok_s[64];
    __shared__ int flag_s[64];

    const int tid  = threadIdx.x;
    const int wave = tid >> 6;
    const int lane = tid & 63;
    const int quad = lane >> 4;
    const int l15  = lane & 15;
    const int wm   = wave >> 1;
    const int wn   = wave & 1;
    const int tile_m = blockIdx.x;
    const int tile_n = blockIdx.y;

    if (tid < 64) {
        int t = token[tile_m * 64 + tid];
        tok_s[tid]  = t;
        flag_s[tid] = need_mapper[t];
    }
    __syncthreads();   // drains everything; manual vmcnt counts start at 0

    // A reg-staging: thread -> row tid>>2 (0..63), 32B source chunk tid&3.
    // LDS slot for source chunk c of row r is c ^ ((r>>1)&3) [16B chunks].
    const int rA_row = tid >> 2;
    const int rA_c   = tid & 3;
    const float* pA  = emb + (size_t)tok_s[rA_row] * DIM + rA_c * 8;
    const int wAidx  = rA_row * 32 + ((rA_c ^ ((rA_row >> 1) & 3)) << 3);  // ushort idx

    // B staging via gload_lds (linear dest): thread tid -> row tid>>2, slot tid&3.
    // Pre-swizzled SOURCE chunk so LDS layout matches the swizzled read.
    const int rb = tid >> 2, sb = tid & 3;
    const unsigned short* pB0 = Bt + (size_t)(tile_n * 128 + rb) * DIM + ((sb ^ ((rb >> 1) & 3)) << 3);
    const unsigned short* pB1 = Bt + (size_t)(tile_n * 128 + 64 + rb) * DIM + ((sb ^ (((64 + rb) >> 1) & 3)) << 3);

#define GLOADB(b, kk) do { \
    gload_lds16(pB0 + (kk), &Bs[(b)][wave * 512]); \
    gload_lds16(pB1 + (kk), &Bs[(b)][2048 + wave * 512]); \
} while (0)

#define WRITEA(b, ra, rb_) do { \
    unsigned u0 = __float_as_uint((ra)[0]) + 0x8000u; \
    unsigned u1 = __float_as_uint((ra)[1]) + 0x8000u; \
    unsigned u2 = __float_as_uint((ra)[2]) + 0x8000u; \
    unsigned u3 = __float_as_uint((ra)[3]) + 0x8000u; \
    unsigned u4 = __float_as_uint((rb_)[0]) + 0x8000u; \
    unsigned u5 = __float_as_uint((rb_)[1]) + 0x8000u; \
    unsigned u6 = __float_as_uint((rb_)[2]) + 0x8000u; \
    unsigned u7 = __float_as_uint((rb_)[3]) + 0x8000u; \
    union { int i4[4]; short8 s; } pk; \
    pk.i4[0] = __builtin_amdgcn_perm(u1, u0, 0x07060302); \
    pk.i4[1] = __builtin_amdgcn_perm(u3, u2, 0x07060302); \
    pk.i4[2] = __builtin_amdgcn_perm(u5, u4, 0x07060302); \
    pk.i4[3] = __builtin_amdgcn_perm(u7, u6, 0x07060302); \
    *(short8*)(&As[(b)][wAidx]) = pk.s; \
} while (0)

    f32x4 acc[2][4] = {};

#define COMPUTE(b) do { \
    short8 af[2], bf[4]; \
    _Pragma("unroll") \
    for (int i = 0; i < 2; ++i) { \
        const int m = wm * 32 + i * 16 + l15; \
        af[i] = *(const short8*)(&As[(b)][m * 32 + ((quad ^ ((m >> 1) & 3)) << 3)]); \
    } \
    _Pragma("unroll") \
    for (int j = 0; j < 4; ++j) { \
        const int n = wn * 64 + j * 16 + l15; \
        bf[j] = *(const short8*)(&Bs[(b)][n * 32 + ((quad ^ ((n >> 1) & 3)) << 3)]); \
    } \
    _Pragma("unroll") \
    for (int i = 0; i < 2; ++i) \
        _Pragma("unroll") \
        for (int j = 0; j < 4; ++j) \
            acc[i][j] = __builtin_amdgcn_mfma_f32_16x16x32_bf16(af[i], bf[j], acc[i][j], 0, 0, 0); \
} while (0)

// One K-step: stage B(T+1) -> Bs[cur^1]; issue A(T+2) -> RD regs; compute tile T;
// convert+write A(T+1) (RC regs, issued last step -> ~1.7 steps of flight);
// vmcnt(2) leaves only A(T+2) flying; one barrier.
#define ITER_BODY(T, RCa, RCb, RDa, RDb) do { \
    GLOADB(cur ^ 1, ((T) + 1) * 32); \
    __builtin_amdgcn_sched_barrier(0); \
    RDa = *(const f32x4*)(pA + ((T) + 2) * 32); \
    RDb = *(const f32x4*)(pA + ((T) + 2) * 32 + 4); \
    COMPUTE(cur); \
    WRITEA(cur ^ 1, RCa, RCb); \
    asm volatile("s_waitcnt vmcnt(2)" ::: "memory"); \
    __builtin_amdgcn_sched_barrier(0); \
    asm volatile("s_waitcnt lgkmcnt(0)" ::: "memory"); \
    __builtin_amdgcn_sched_barrier(0); \
    __builtin_amdgcn_s_barrier(); \
    cur ^= 1; \
} while (0)

    f32x4 rTa, rTb, rA0a, rA0b, rA1a, rA1b;

    // Prologue: stage tile 0 (A via regs, B via gload_lds), prefetch A(1).
    rTa = *(const f32x4*)(pA);
    rTb = *(const f32x4*)(pA + 4);
    GLOADB(0, 0);
    __builtin_amdgcn_sched_barrier(0);
    rA0a = *(const f32x4*)(pA + 32);
    rA0b = *(const f32x4*)(pA + 36);
    WRITEA(0, rTa, rTb);                       // compiler waits A(0) loads
    asm volatile("s_waitcnt vmcnt(2)" ::: "memory");   // B(0) landed; A(1) flying
    __builtin_amdgcn_sched_barrier(0);
    asm volatile("s_waitcnt lgkmcnt(0)" ::: "memory");
    __builtin_amdgcn_sched_barrier(0);
    __builtin_amdgcn_s_barrier();

    int cur = 0;
#pragma unroll 1
    for (int t = 0; t < 22; t += 2) {
        ITER_BODY(t,     rA0a, rA0b, rA1a, rA1b);   // consume A(t+1), issue A(t+2)
        ITER_BODY(t + 1, rA1a, rA1b, rA0a, rA0b);
    }
    // t = 22: stage tile 23 (A(23) already in rA0; B via gload_lds), compute 22.
    GLOADB(cur ^ 1, 23 * 32);
    __builtin_amdgcn_sched_barrier(0);
    COMPUTE(cur);
    WRITEA(cur ^ 1, rA0a, rA0b);
    asm volatile("s_waitcnt vmcnt(0)" ::: "memory");
    __builtin_amdgcn_sched_barrier(0);
    asm volatile("s_waitcnt lgkmcnt(0)" ::: "memory");
    __builtin_amdgcn_sched_barrier(0);
    __builtin_amdgcn_s_barrier();
    cur ^= 1;
    COMPUTE(cur);                              // tile 23

    // Epilogue. C/D layout: col = lane&15, row = quad*4 + reg.
    const int colg = tile_n * 128 + wn * 64 + l15;
    float bv[4];
#pragma unroll
    for (int j = 0; j < 4; ++j) bv[j] = bias[colg + j * 16];

#pragma unroll
    for (int i = 0; i < 2; ++i) {
#pragma unroll
        for (int r = 0; r < 4; ++r) {
            const int lrow = wm * 32 + i * 16 + quad * 4 + r;
            const int gm   = tile_m * 64 + lrow;
            float* orow = out + (size_t)gm * DIM + colg;
            if (flag_s[lrow]) {
#pragma unroll
                for (int j = 0; j < 4; ++j)
                    orow[j * 16] = acc[i][j][r] + bv[j];
            } else {
                const float* erow = emb + (size_t)tok_s[lrow] * DIM + colg;
#pragma unroll
                for (int j = 0; j < 4; ++j)
                    orow[j * 16] = erow[j * 16];
            }
        }
    }
#undef GLOADB
#undef WRITEA
#undef COMPUTE
#undef ITER_BODY
}

extern "C" void kernel_launch(void* const* d_in, const int* in_sizes, int n_in,
                              void* d_out, int out_size, void* d_ws, size_t ws_size,
                              hipStream_t stream)
{
    const int*   token       = (const int*)d_in[0];
    const int*   need_mapper = (const int*)d_in[1];
    const float* emb         = (const float*)d_in[2];
    const float* w           = (const float*)d_in[3];
    const float* bias        = (const float*)d_in[4];
    float* out = (float*)d_out;

    const int ntok = in_sizes[0];   // 32*512 = 16384

    unsigned short* Bt = (unsigned short*)d_ws;   // 768*768 bf16 = 1.18 MB

    convw_kernel<<<dim3(DIM / 64, DIM / 64), dim3(256), 0, stream>>>(w, Bt);
    fused_gemm_kernel<<<dim3(ntok / 64, DIM / 128), dim3(256), 0, stream>>>(
        token, need_mapper, emb, Bt, bias, out);
}

// Round 8
// 241.600 us; speedup vs baseline: 1.0450x; 1.0450x over previous
//
#include <hip/hip_runtime.h>
#include <hip/hip_bf16.h>
#include <stdint.h>
#include <stddef.h>

#define DIM 768

typedef short short8 __attribute__((ext_vector_type(8)));
typedef float f32x4 __attribute__((ext_vector_type(4)));

__device__ inline unsigned short f2bf_rne(float f) {
    union { float f; unsigned u; } x; x.f = f;
    unsigned r = x.u + 0x7fffu + ((x.u >> 16) & 1u);
    return (unsigned short)(r >> 16);
}

__device__ inline void gload_lds16(const void* g, void* l) {
    __builtin_amdgcn_global_load_lds((const __attribute__((address_space(1))) void*)g,
                                     (__attribute__((address_space(3))) void*)l, 16, 0, 0);
}

// Kernel 1: W [K][N] fp32 -> Bt [N][K] bf16 via LDS transpose (coalesced read AND write).
__global__ __launch_bounds__(256) void convw_kernel(
    const float* __restrict__ w, unsigned short* __restrict__ Bt)
{
    __shared__ unsigned short t[64][65];
    const int k0 = blockIdx.x * 64, n0 = blockIdx.y * 64;
    const int tid = threadIdx.x;
#pragma unroll
    for (int p = 0; p < 16; ++p) {
        int e = p * 256 + tid;
        int r = e >> 6, c = e & 63;              // r: k-row, c: n-col
        t[c][r] = f2bf_rne(w[(size_t)(k0 + r) * DIM + n0 + c]);
    }
    __syncthreads();
#pragma unroll
    for (int p = 0; p < 16; ++p) {
        int e = p * 256 + tid;
        int r = e >> 6, c = e & 63;              // r: n-row, c: k-col
        Bt[(size_t)(n0 + r) * DIM + k0 + c] = t[r][c];
    }
}

// Kernel 2: fused gather + GEMM + conditional select.
// Block = 128 m-rows x 128 n-cols, BK=32, 4 waves, 4x4 16x16x32 bf16 MFMA per wave.
// A is gathered fp32 directly from the embedding table into LDS (XOR-swizzled chunk
// slots to kill the 128B-stride bank conflict), converted to bf16 in-register.
// need==0 rows are written from an L2-warm re-read of the embedding row in the epilogue.
//
// Session verdict (8 structurally diverse variants, rounds 0-7): this baseline
// structure measured best twice (242.8 / 241.9 us). Total dur_us decomposes as
// ~186 us of harness poison-fills (2x ~93 us fillBufferAligned, visible in every
// profile) + ~56 us kernel slice. The slice is latency-bound on the scattered
// 128-row gather (r3 counters on a sibling: MfmaUtil 7.5%, Occ 16%, FETCH=ideal
// bytes) and proved insensitive-to-negative to: double-buffered LDS (285.7),
// counted s_waitcnt vmcnt(N) + raw barriers (244.6), 64-row tiles for 2x TLP
// (262.8), A reg-staging with 2-deep pipeline (252.5), token compaction +
// dense GEMM at half FLOPs (253.2-256.8), and XCD-aware grid swizzles.
__global__ __launch_bounds__(256) void fused_gemm_kernel(
    const int* __restrict__ token,
    const int* __restrict__ need_mapper,
    const float* __restrict__ emb,
    const unsigned short* __restrict__ Bt,   // [768][768] bf16, n-major
    const float* __restrict__ bias,
    float* __restrict__ out)                 // [M][768] fp32
{
    __shared__ float As[128 * 32];            // 16 KB, chunk-swizzled
    __shared__ unsigned short Bs[128 * 32];   // 8 KB
    __shared__ int tok_s[128];
    __shared__ int flag_s[128];

    const int tid  = threadIdx.x;
    const int wave = tid >> 6;
    const int lane = tid & 63;
    const int quad = lane >> 4;
    const int l15  = lane & 15;
    const int wm   = wave >> 1;
    const int wn   = wave & 1;
    const int tile_m = blockIdx.x;
    const int tile_n = blockIdx.y;

    if (tid < 128) {
        int t = token[tile_m * 128 + tid];
        tok_s[tid]  = t;
        flag_s[tid] = need_mapper[t];
    }
    __syncthreads();

    // A staging: issue j covers rows j*32..j*32+31; lane l -> row +(l>>3), chunk slot l&7.
    // Slot s of row r holds source chunk (s ^ (r&7))  [XOR swizzle].
    const int r8 = tid >> 3;
    const int c8 = tid & 7;
    const float* pA[4];
#pragma unroll
    for (int j = 0; j < 4; ++j) {
        int r = j * 32 + r8;
        pA[j] = emb + (size_t)tok_s[r] * DIM + ((c8 ^ (r & 7)) << 2);
    }
    float* lA0 = As + (wave * 8) * 32;        // wave-uniform LDS bases
    // B staging: row = tid>>2 (+64 on 2nd issue), 8-ushort chunk = (tid&3)*8.
    const unsigned short* pB = Bt + (size_t)(tile_n * 128 + (tid >> 2)) * DIM + (tid & 3) * 8;
    unsigned short* lB = Bs + wave * 512;

    f32x4 acc[4][4] = {};

    for (int kk = 0; kk < DIM; kk += 32) {
        __syncthreads();
#pragma unroll
        for (int j = 0; j < 4; ++j)
            gload_lds16(pA[j] + kk, lA0 + j * 32 * 32);
        gload_lds16(pB + kk,                   lB);
        gload_lds16(pB + kk + (size_t)64 * DIM, lB + 2048);
        __syncthreads();

        short8 af[4], bf[4];
#pragma unroll
        for (int i = 0; i < 4; ++i) {
            const int m = wm * 64 + i * 16 + l15;
            const float* row = As + (m << 5);
            f32x4 a0 = *(const f32x4*)(row + ((((quad << 1)    ) ^ (m & 7)) << 2));
            f32x4 a1 = *(const f32x4*)(row + ((((quad << 1) + 1) ^ (m & 7)) << 2));
            unsigned u0 = __float_as_uint(a0[0]) + 0x8000u;
            unsigned u1 = __float_as_uint(a0[1]) + 0x8000u;
            unsigned u2 = __float_as_uint(a0[2]) + 0x8000u;
            unsigned u3 = __float_as_uint(a0[3]) + 0x8000u;
            unsigned u4 = __float_as_uint(a1[0]) + 0x8000u;
            unsigned u5 = __float_as_uint(a1[1]) + 0x8000u;
            unsigned u6 = __float_as_uint(a1[2]) + 0x8000u;
            unsigned u7 = __float_as_uint(a1[3]) + 0x8000u;
            union { int i4[4]; short8 s; } pk;
            pk.i4[0] = __builtin_amdgcn_perm(u1, u0, 0x07060302);
            pk.i4[1] = __builtin_amdgcn_perm(u3, u2, 0x07060302);
            pk.i4[2] = __builtin_amdgcn_perm(u5, u4, 0x07060302);
            pk.i4[3] = __builtin_amdgcn_perm(u7, u6, 0x07060302);
            af[i] = pk.s;
        }
#pragma unroll
        for (int j = 0; j < 4; ++j)
            bf[j] = *(const short8*)(Bs + (wn * 64 + j * 16 + l15) * 32 + quad * 8);
#pragma unroll
        for (int i = 0; i < 4; ++i)
#pragma unroll
            for (int j = 0; j < 4; ++j)
                acc[i][j] = __builtin_amdgcn_mfma_f32_16x16x32_bf16(af[i], bf[j], acc[i][j], 0, 0, 0);
    }

    // Epilogue. C/D layout: col = lane&15, row = quad*4 + reg.
    const int colg = tile_n * 128 + wn * 64 + l15;
    float bv[4];
#pragma unroll
    for (int j = 0; j < 4; ++j) bv[j] = bias[colg + j * 16];

#pragma unroll
    for (int i = 0; i < 4; ++i) {
#pragma unroll
        for (int r = 0; r < 4; ++r) {
            const int lrow = wm * 64 + i * 16 + quad * 4 + r;
            const int gm   = tile_m * 128 + lrow;
            float* orow = out + (size_t)gm * DIM + colg;
            if (flag_s[lrow]) {
#pragma unroll
                for (int j = 0; j < 4; ++j)
                    orow[j * 16] = acc[i][j][r] + bv[j];
            } else {
                const float* erow = emb + (size_t)tok_s[lrow] * DIM + colg;
#pragma unroll
                for (int j = 0; j < 4; ++j)
                    orow[j * 16] = erow[j * 16];
            }
        }
    }
}

extern "C" void kernel_launch(void* const* d_in, const int* in_sizes, int n_in,
                              void* d_out, int out_size, void* d_ws, size_t ws_size,
                              hipStream_t stream)
{
    const int*   token       = (const int*)d_in[0];
    const int*   need_mapper = (const int*)d_in[1];
    const float* emb         = (const float*)d_in[2];
    const float* w           = (const float*)d_in[3];
    const float* bias        = (const float*)d_in[4];
    float* out = (float*)d_out;

    const int ntok = in_sizes[0];   // 32*512 = 16384

    unsigned short* Bt = (unsigned short*)d_ws;   // 768*768 bf16 = 1.18 MB

    convw_kernel<<<dim3(DIM / 64, DIM / 64), dim3(256), 0, stream>>>(w, Bt);
    fused_gemm_kernel<<<dim3(ntok / 128, DIM / 128), dim3(256), 0, stream>>>(
        token, need_mapper, emb, Bt, bias, out);
}